// Round 6
// baseline (142.305 us; speedup 1.0000x reference)
//
#include <hip/hip_runtime.h>
#include <math.h>

// B=16, C_IN=256, C_OUT=256, H=W=64, K=3, NK=2
// weights: [2][256][256][3][3]; bank stride 589824 floats; per-o stride 2304.
//
// Pipeline:
//  1. scale_kernel: per (b,o) demod scale -> ws[scale]
//  2. wprep: combined+modulated+demod weights -> bf16 wq, LDS-image layout
//     per (b,ot2,c16): [p=20][ol=128][e=8], p = io*10 + j (j=9 zero dummy tap).
//  3. xprep: x -> bf16 xq [b][c16][rowp 66][colp 66][i 16], halo zeros baked,
//     PRE-SWIZZLED (XOR bank swizzle baked into storage order) so conv can
//     global_load_lds linearly and ds_read with the matching XOR.
//  4. conv_mfma: implicit GEMM via mfma_f32_16x16x32_bf16. Block = 512 thr
//     (8 waves) = 128 o x 8 rows x 64 px; grid 256; phase-split K-loop:
//     5 MFMA clusters per c-step, staging GLL issued phases 0-2, ONE raw
//     s_barrier + one pre-covered vmcnt(0) per c-step, setprio around MFMA.
//  5. norm_kernel: channel RMSNorm * gamma * 16 + SiLU in place.

typedef __attribute__((ext_vector_type(8))) short short8;
typedef __attribute__((ext_vector_type(4))) float f32x4;

#define GLL16(src, dst)                                                       \
  __builtin_amdgcn_global_load_lds(                                           \
      (const __attribute__((address_space(1))) unsigned int*)(src),           \
      (__attribute__((address_space(3))) unsigned int*)(dst), 16, 0, 0)

static __device__ __forceinline__ unsigned short f2bf(float v) {
  union { float f; unsigned u; } u;
  u.f = v;
  unsigned r = u.u + 0x7FFF + ((u.u >> 16) & 1);  // RNE
  return (unsigned short)(r >> 16);
}

// ---------------------------------------------------------------------------
// Kernel 1: per-(b,o) demodulation scale
// ---------------------------------------------------------------------------
__global__ __launch_bounds__(256) void scale_kernel(
    const float* __restrict__ mod, const float* __restrict__ kmod,
    const float* __restrict__ weights, float* __restrict__ scale) {
  int bo = blockIdx.x;
  int b = bo >> 8, o = bo & 255;

  float k0 = kmod[b * 2 + 0], k1 = kmod[b * 2 + 1];
  float mx = fmaxf(k0, k1);
  float e0 = expf(k0 - mx), e1 = expf(k1 - mx);
  float ai = 1.0f / (e0 + e1);
  float a0 = e0 * ai, a1 = e1 * ai;

  int t = threadIdx.x;
  const float* w0 = weights + (size_t)o * 2304;
  const float* w1 = w0 + 589824;

  float s = 0.0f;
#pragma unroll
  for (int r = 0; r < 9; r++) {
    int idx = t + r * 256;
    int i = idx / 9;
    float wv = a0 * w0[idx] + a1 * w1[idx];
    wv *= (mod[b * 256 + i] + 1.0f);
    s += wv * wv;
  }
#pragma unroll
  for (int off = 32; off > 0; off >>= 1) s += __shfl_down(s, off);

  __shared__ float red[4];
  if ((t & 63) == 0) red[t >> 6] = s;
  __syncthreads();
  if (t == 0) {
    float tot = red[0] + red[1] + red[2] + red[3];
    scale[bo] = rsqrtf(fmaxf(tot, 1e-8f));
  }
}

// ---------------------------------------------------------------------------
// Kernel 2: weight prep -> bf16 LDS-image in wq. Block = (b, ot2, c): 512 blks.
// Chunk = [p20][ol128][e8] = 20480 ushort = 40960 B.
// ---------------------------------------------------------------------------
__global__ __launch_bounds__(256) void wprep(
    const float* __restrict__ mod, const float* __restrict__ kmod,
    const float* __restrict__ weights, const float* __restrict__ scale,
    unsigned short* __restrict__ wq) {
  __shared__ __align__(16) unsigned short buf[20480];
  int blk = blockIdx.x;                 // b*32 + ot*16 + c
  int b = blk >> 5, ot = (blk >> 4) & 1, c = blk & 15;
  int t = threadIdx.x;

  float k0 = kmod[b * 2 + 0], k1 = kmod[b * 2 + 1];
  float mx = fmaxf(k0, k1);
  float e0 = expf(k0 - mx), e1 = expf(k1 - mx);
  float ai = 1.0f / (e0 + e1);
  float a0 = e0 * ai, a1 = e1 * ai;

  // zero the two dummy-tap rows (p=9, p=19): 2048 elems
#pragma unroll
  for (int k = 0; k < 8; ++k) {
    int e = t + k * 256;
    int half = e >> 10;
    buf[(half * 10 + 9) * 1024 + (e & 1023)] = 0;
  }

  int ol = t >> 1, eh = t & 1;
  int o = ot * 128 + ol;
  float sc = scale[b * 256 + o];
#pragma unroll
  for (int io = 0; io < 2; ++io) {
#pragma unroll
    for (int eo = 0; eo < 4; ++eo) {
      int e = eh * 4 + eo;
      int i = c * 16 + io * 8 + e;
      float f = (mod[b * 256 + i] + 1.0f) * sc;
      const float* w0 = &weights[((size_t)o * 256 + i) * 9];
      const float* w1 = w0 + 589824;
#pragma unroll
      for (int j = 0; j < 9; ++j) {
        float v = (a0 * w0[j] + a1 * w1[j]) * f;
        buf[(io * 10 + j) * 1024 + ol * 8 + e] = f2bf(v);
      }
    }
  }
  __syncthreads();
  size_t base = (size_t)blk * 20480;
#pragma unroll
  for (int k = 0; k < 10; ++k) {
    int idx = t + k * 256;
    *(short8*)(wq + base + (size_t)idx * 8) = *(const short8*)&buf[idx * 8];
  }
}

// ---------------------------------------------------------------------------
// Kernel 3: x prep -> bf16 xq, pre-swizzled.
// Plane (b,c,rowp) = 1056 elems = 132 16B-groups. Group t's data goes to
// group t ^ flip, flip = bit3(globalGroup) ^ (bc&1)  (window-start parity).
// ---------------------------------------------------------------------------
__global__ __launch_bounds__(256) void xprep(
    const float* __restrict__ x, unsigned short* __restrict__ xq) {
  int blk = blockIdx.x;  // (b*16 + c)*66 + rowp
  int rowp = blk % 66;
  int bc = blk / 66;
  int b = bc >> 4, c = bc & 15;
  int t = threadIdx.x;
  size_t obase = (size_t)blk * 1056;

  if (rowp == 0 || rowp == 65) {
    for (int idx = t; idx < 1056; idx += 256) xq[obase + idx] = 0;
    return;
  }
  __shared__ __align__(16) unsigned short xs2[1056];
  int row = rowp - 1;
  for (int idx = t; idx < 1056; idx += 256) xs2[idx] = 0;
  __syncthreads();
#pragma unroll
  for (int k = 0; k < 4; ++k) {
    int idx = t + k * 256;  // 0..1023
    int il = idx >> 6, col = idx & 63;
    float v = x[(((size_t)b * 256 + c * 16 + il) * 64 + row) * 64 + col];
    xs2[(col + 1) * 16 + il] = f2bf(v);
  }
  __syncthreads();
  if (t < 132) {
    int G = blk * 132 + t;                       // global 16B-group index
    int flip = ((G >> 3) & 1) ^ (bc & 1);        // LDS-byte-bit7 of this group
    *(short8*)(xq + obase + (size_t)(t ^ flip) * 8) = *(const short8*)&xs2[t * 8];
  }
}

// ---------------------------------------------------------------------------
// Kernel 4: implicit-GEMM conv, phase-split pipeline.
// Grid 256 (XCD-clustered); block 512 thr (8 waves), wave = out row.
// ---------------------------------------------------------------------------
__global__ __launch_bounds__(512, 2) void conv_mfma(
    const unsigned short* __restrict__ xq, const unsigned short* __restrict__ wq,
    float* __restrict__ out) {
  __shared__ __align__(16) unsigned short wsm[2][20480];  // [p20][ol128][e8] 40 KB x2
  __shared__ __align__(16) unsigned short xsm[2][10560];  // [rl10][colp66][i16] 20.6 KB x2

  int bid = blockIdx.x;
  int xcd = bid & 7;
  int kk = bid >> 3;           // 0..31
  int b = xcd * 2 + (kk >> 4); // 2 batches per XCD
  int rem = kk & 15;
  int ot = rem >> 3;           // 128-o half
  int rt = rem & 7;            // 8-row tile
  int r0 = rt * 8;

  int t = threadIdx.x;
  int w = t >> 6, lane = t & 63;
  int g = (t >> 4) & 3, lm = t & 15;

  // per-s LDS read offsets (bytes), loop-invariant across c
  int baddr_[5], aaddr_[5];
#pragma unroll
  for (int s = 0; s < 5; ++s) {
    int p = 4 * s + g;
    int io = (p >= 10) ? 1 : 0;
    int j = p - 10 * io;
    int jd3, jm3;
    if (j == 9) { jd3 = 0; jm3 = 0; }  // dummy tap: weights zero
    else { jd3 = (j >= 3) + (j >= 6); jm3 = j - 3 * jd3; }
    int ba = ((w + jd3) * 66 + lm + jm3) * 32 + io * 16;
    ba ^= ((ba >> 7) & 1) << 4;  // matches xprep pre-swizzle
    baddr_[s] = ba;              // + nf*512 at use (doesn't touch bit7)
    aaddr_[s] = p * 2048 + lm * 16;  // + mf*256 at use
  }

  f32x4 acc[8][4];
#pragma unroll
  for (int mf = 0; mf < 8; ++mf)
#pragma unroll
    for (int nf = 0; nf < 4; ++nf) acc[mf][nf] = (f32x4){0.f, 0.f, 0.f, 0.f};

  // staging: w = 5 GLL rounds (40960 B), x = 2 full + 1 partial round (21120 B)
#define WGLL(cn, nb, r)                                                        \
  {                                                                            \
    const unsigned short* s_ = wq + ((size_t)(b * 32 + ot * 16 + (cn))) * 20480 \
                               + ((r) * 512 + w * 64 + lane) * 8;              \
    GLL16(s_, &wsm[nb][(r) * 4096 + w * 512]);                                 \
  }
#define XGLL(cn, nb, r)                                                        \
  {                                                                            \
    const unsigned short* s_ = xq + ((size_t)((b * 16 + (cn)) * 66 + r0)) * 1056 \
                               + ((r) * 512 + w * 64 + lane) * 8;              \
    GLL16(s_, &xsm[nb][(r) * 4096 + w * 512]);                                 \
  }

  // prologue: stage c=0 into buffer 0
  WGLL(0, 0, 0); WGLL(0, 0, 1); WGLL(0, 0, 2); WGLL(0, 0, 3); WGLL(0, 0, 4);
  XGLL(0, 0, 0); XGLL(0, 0, 1);
  if (t < 296) XGLL(0, 0, 2);
  asm volatile("s_waitcnt vmcnt(0)" ::: "memory");
  __builtin_amdgcn_s_barrier();
  __builtin_amdgcn_sched_barrier(0);

  for (int c = 0; c < 16; ++c) {
    int cur = c & 1;
    const char* wsb = (const char*)wsm[cur];
    const char* xsb = (const char*)xsm[cur];
#pragma unroll
    for (int s = 0; s < 5; ++s) {
      // staging issue for c+1, front-loaded into phases 0-2
      if (c < 15) {
        int nb = cur ^ 1;
        if (s == 0) { WGLL(c + 1, nb, 0); WGLL(c + 1, nb, 1); XGLL(c + 1, nb, 0); }
        if (s == 1) { WGLL(c + 1, nb, 2); WGLL(c + 1, nb, 3); XGLL(c + 1, nb, 1); }
        if (s == 2) { WGLL(c + 1, nb, 4); if (t < 296) XGLL(c + 1, nb, 2); }
      }
      short8 A[8];
#pragma unroll
      for (int mf = 0; mf < 8; ++mf)
        A[mf] = *(const short8*)(wsb + aaddr_[s] + mf * 256);
      __builtin_amdgcn_s_setprio(1);
#pragma unroll
      for (int nf = 0; nf < 4; ++nf) {
        short8 Bf = *(const short8*)(xsb + baddr_[s] + nf * 512);
#pragma unroll
        for (int mf = 0; mf < 8; ++mf)
          acc[mf][nf] =
              __builtin_amdgcn_mfma_f32_16x16x32_bf16(A[mf], Bf, acc[mf][nf], 0, 0, 0);
      }
      __builtin_amdgcn_s_setprio(0);
    }
    // once per c-step: staged loads (issued >=2 phases ago) must land before
    // any wave reads buf^1 next step. Pre-covered -> near-zero wait.
    asm volatile("s_waitcnt vmcnt(0)" ::: "memory");
    __builtin_amdgcn_s_barrier();
    __builtin_amdgcn_sched_barrier(0);
  }

  // ---- epilogue: D col=lane&15 (px), row-in-frag=4*(lane>>4)+q (o) ----
  int row = r0 + w;
#pragma unroll
  for (int mf = 0; mf < 8; ++mf)
#pragma unroll
    for (int nf = 0; nf < 4; ++nf)
#pragma unroll
      for (int q = 0; q < 4; ++q) {
        int o = ot * 128 + mf * 16 + g * 4 + q;
        int col = nf * 16 + lm;
        out[(((size_t)b * 256 + o) * 64 + row) * 64 + col] = acc[mf][nf][q];
      }
#undef WGLL
#undef XGLL
}

// ---------------------------------------------------------------------------
// Kernel 5: channel RMSNorm * gamma * 16 + SiLU, in place.
// ---------------------------------------------------------------------------
__global__ __launch_bounds__(256) void norm_kernel(
    float* __restrict__ y, const float* __restrict__ gamma) {
  int blk = blockIdx.x;
  int b = blk >> 6, h = blk & 63;
  int t = threadIdx.x;
  int p = t & 63, og = t >> 6;

  size_t base = (((size_t)b * 256) * 64 + h) * 64 + p;
  float yv[64];
  float s = 0.0f;
#pragma unroll
  for (int k = 0; k < 64; k++) {
    yv[k] = y[base + (size_t)(og * 64 + k) * 4096];
    s = fmaf(yv[k], yv[k], s);
  }

  __shared__ float red[4][64];
  __shared__ float invs[64];
  red[og][p] = s;
  __syncthreads();
  if (og == 0) {
    float tot = red[0][p] + red[1][p] + red[2][p] + red[3][p];
    float nrm = sqrtf(tot);
    invs[p] = 16.0f / fmaxf(nrm, 1e-12f);
  }
  __syncthreads();
  float iv = invs[p];
#pragma unroll
  for (int k = 0; k < 64; k++) {
    int o = og * 64 + k;
    float v = yv[k] * iv * gamma[o];
    float sg = 1.0f / (1.0f + expf(-v));
    y[base + (size_t)o * 4096] = v * sg;
  }
}

extern "C" void kernel_launch(void* const* d_in, const int* in_sizes, int n_in,
                              void* d_out, int out_size, void* d_ws, size_t ws_size,
                              hipStream_t stream) {
  const float* x = (const float*)d_in[0];
  const float* mod = (const float*)d_in[1];
  const float* kmod = (const float*)d_in[2];
  const float* weights = (const float*)d_in[3];
  const float* gamma = (const float*)d_in[4];
  float* out = (float*)d_out;

  // ws layout: wq 20,971,520 B | scale 16,384 B | xq 35,684,352 B  (~56.7 MB)
  unsigned short* wq = (unsigned short*)d_ws;
  float* scale = (float*)((char*)d_ws + 20971520);
  unsigned short* xq = (unsigned short*)((char*)d_ws + 20987904);

  scale_kernel<<<16 * 256, 256, 0, stream>>>(mod, kmod, weights, scale);
  wprep<<<512, 256, 0, stream>>>(mod, kmod, weights, scale, wq);
  xprep<<<16 * 16 * 66, 256, 0, stream>>>(x, xq);
  conv_mfma<<<256, 512, 0, stream>>>(xq, wq, out);
  norm_kernel<<<16 * 64, 256, 0, stream>>>(out, gamma);
}